// Round 4
// baseline (725.771 us; speedup 1.0000x reference)
//
#include <hip/hip_runtime.h>
#include <hip/hip_bf16.h>
#include <math.h>

#define B_ 4
#define C_ 200
#define W_ 300
#define H_ 128
#define NH_ 8
#define PH_ 16
#define FF_ 512
#define L_ 2
#define MAXLEN_ 200
#define PEN_ 512

// Generic float load: F32=1 -> fp32 buffer, F32=0 -> bf16 buffer (bit-exact widen).
template <int F32>
__device__ __forceinline__ float ldf(const void* __restrict__ p, int i) {
    if (F32) return ((const float*)p)[i];
    return __uint_as_float(((unsigned int)((const unsigned short*)p)[i]) << 16);
}

// ---------------- input dtype detector: writes 1 (fp32) or 0 (bf16) to *flag
__global__ void detect_kernel(const unsigned int* __restrict__ chars_raw, int* __restrict__ flag) {
    __shared__ int cnt;
    if (threadIdx.x == 0) cnt = 0;
    __syncthreads();
    int sane = 0;
    for (int i = threadIdx.x; i < 2048; i += 256) {
        unsigned int u = chars_raw[i];
        unsigned int e = (u >> 23) & 0xFFu;
        if (e >= 0x60u && e <= 0x9Fu) sane++;
    }
    atomicAdd(&cnt, sane);
    __syncthreads();
    if (threadIdx.x == 0) *flag = (cnt > 1024) ? 1 : 0;
}

// ---------------- PEW[t][p][h] = sum_j PE[p][j] * Wf[t*128+j][h]
template <int F32>
__global__ void pew_kernel(const int* __restrict__ flag,
                           const void* __restrict__ Wf, float* __restrict__ PEW) {
    if (*flag != F32) return;
    __shared__ float pe[H_];
    int p = blockIdx.x, t = threadIdx.x;  // 128 threads
    {
        int j = (t < 64) ? t : (t - 64);
        double f = exp(-(double)j * (log(10000.0) / 63.0));
        double a = (double)p * f;
        pe[t] = (float)((t < 64) ? sin(a) : cos(a));
    }
    __syncthreads();
    for (int q = 0; q < 4; ++q) {
        float acc = 0.f;
        int base = (q * H_) * H_ + t;
        for (int j = 0; j < H_; ++j)
            acc += pe[j] * ldf<F32>(Wf, base + j * H_);
        PEW[((q * PEN_) + p) * H_ + t] = acc;
    }
}

// ---------------- k/v for both layers: kbuf[((l*B+b)*W+w)*H+h]
template <int F32>
__global__ void kv_kernel(const int* __restrict__ flag,
                          const void* __restrict__ words,
                          const void* __restrict__ Wk, const void* __restrict__ bk,
                          const void* __restrict__ Wv, const void* __restrict__ bv,
                          float* __restrict__ kbuf, float* __restrict__ vbuf) {
    if (*flag != F32) return;
    __shared__ float row[H_];
    int blk = blockIdx.x;                 // l*B*W + b*W + w
    int li = blk / (B_ * W_);
    int rem = blk % (B_ * W_);
    int t = threadIdx.x;                  // 128
    row[t] = ldf<F32>(words, rem * H_ + t);
    __syncthreads();
    int wkb = li * H_ * H_;
    float ak = ldf<F32>(bk, li * H_ + t);
    float av = ldf<F32>(bv, li * H_ + t);
    for (int j = 0; j < H_; ++j) {
        float x = row[j];
        ak += x * ldf<F32>(Wk, wkb + j * H_ + t);
        av += x * ldf<F32>(Wv, wkb + j * H_ + t);
    }
    kbuf[blk * H_ + t] = ak;
    vbuf[blk * H_ + t] = av;
}

// ---------------- block-wide sum of 128 values (t<128 contribute v)
__device__ __forceinline__ float block_sum_128(int t, float v, float* s_red) {
    __syncthreads();
    if (t < 128) s_red[t] = v;
    __syncthreads();
    if (t < 64) {
        float x = s_red[t] + s_red[t + 64];
        #pragma unroll
        for (int off = 32; off > 0; off >>= 1) x += __shfl_down(x, off);
        if (t == 0) s_red[0] = x;
    }
    __syncthreads();
    return s_red[0];
}

// ---------------- mega kernel: one block per (b,c), both layers; fp32 output
template <int F32>
__global__ __launch_bounds__(256) void mega_kernel(
    const int* __restrict__ flag,
    const void* __restrict__ chars,
    const int* __restrict__ pos_s, const int* __restrict__ pos_e,
    const int* __restrict__ lex_s, const int* __restrict__ lex_e,
    const int* __restrict__ seq_len, const int* __restrict__ lex_num,
    const void* __restrict__ bfv,
    const void* __restrict__ Wq, const void* __restrict__ bq,
    const void* __restrict__ Wr, const void* __restrict__ br,
    const void* __restrict__ u_bias, const void* __restrict__ v_bias,
    const void* __restrict__ ln1_g, const void* __restrict__ ln1_b,
    const void* __restrict__ ln2_g, const void* __restrict__ ln2_b,
    const void* __restrict__ W1, const void* __restrict__ b1,
    const void* __restrict__ W2, const void* __restrict__ b2,
    const float* __restrict__ PEW, const float* __restrict__ kbuf, const float* __restrict__ vbuf,
    float* __restrict__ out) {
    if (*flag != F32) return;

    __shared__ float s_x[H_], s_qu[H_], s_qv[H_];
    __shared__ float s_wvec[NH_][H_];
    __shared__ float s_bterm[NH_];
    __shared__ float s_sc[NH_][W_];
    __shared__ float s_rel[2][H_];
    __shared__ float s_red[H_];
    __shared__ float s_hid[FF_];
    __shared__ float s_tmp[256];
    __shared__ int s_ls[W_], s_le[W_];

    int blk = blockIdx.x;
    int b = blk / C_, c = blk % C_;
    int t = threadIdx.x;

    if (t < H_) s_x[t] = ldf<F32>(chars, (b * C_ + c) * H_ + t);
    for (int w = t; w < W_; w += 256) {
        s_ls[w] = lex_s[b * W_ + w];
        s_le[w] = lex_e[b * W_ + w];
    }
    int ps = pos_s[b * C_ + c];
    int pev = pos_e[b * C_ + c];
    int cvalid = (c < seq_len[b]);
    int wnum = lex_num[b];
    __syncthreads();

    for (int li = 0; li < L_; ++li) {
        // ---- q projection (+u, +v bias variants)
        if (t < H_) {
            int wqb = li * H_ * H_;
            float acc = ldf<F32>(bq, li * H_ + t);
            for (int j = 0; j < H_; ++j)
                acc += s_x[j] * ldf<F32>(Wq, wqb + j * H_ + t);
            s_qu[t] = acc + ldf<F32>(u_bias, li * H_ + t);
            s_qv[t] = acc + ldf<F32>(v_bias, li * H_ + t);
        }
        __syncthreads();

        // ---- wvec[n][h] = sum_p Wr[h][n*16+p]*qv[n*16+p];  bterm[n] = sum_p br[n*16+p]*qv
        if (t < H_) {
            int wrb = li * H_ * H_ + t * H_;
            for (int n = 0; n < NH_; ++n) {
                float acc = 0.f;
                #pragma unroll
                for (int p = 0; p < PH_; ++p)
                    acc += ldf<F32>(Wr, wrb + n * PH_ + p) * s_qv[n * PH_ + p];
                s_wvec[n][t] = acc;
            }
        } else if (t < H_ + NH_) {
            int n = t - H_;
            float acc = 0.f;
            #pragma unroll
            for (int p = 0; p < PH_; ++p)
                acc += ldf<F32>(br, li * H_ + n * PH_ + p) * s_qv[n * PH_ + p];
            s_bterm[n] = acc;
        }
        __syncthreads();

        // ---- score loop over w (2 per iteration)
        const float* kL = kbuf + (size_t)(li * B_ + b) * W_ * H_;
        for (int w0 = 0; w0 < W_; w0 += 2) {
            __syncthreads();   // protect s_rel vs previous iteration's readers
            {
                int wi = w0 + (t >> 7);
                int h = t & 127;
                int ls = s_ls[wi], le = s_le[wi];
                int i0 = min(max(ps - ls + MAXLEN_, 0), PEN_ - 1);
                int i1 = min(max(ps - le + MAXLEN_, 0), PEN_ - 1);
                int i2 = min(max(pev - ls + MAXLEN_, 0), PEN_ - 1);
                int i3 = min(max(pev - le + MAXLEN_, 0), PEN_ - 1);
                float rv = ldf<F32>(bfv, h)
                    + PEW[(0 * PEN_ + i0) * H_ + h] + PEW[(1 * PEN_ + i1) * H_ + h]
                    + PEW[(2 * PEN_ + i2) * H_ + h] + PEW[(3 * PEN_ + i3) * H_ + h];
                s_rel[t >> 7][h] = fmaxf(rv, 0.f);
            }
            __syncthreads();
            {
                int g = t >> 4;           // 16 groups: (wsel, n)
                int n = g & 7, wsel = g >> 3, p = t & 15;
                int w = w0 + wsel;
                const float* rl = s_rel[wsel];
                const float* wv = s_wvec[n];
                float acc = s_qu[n * PH_ + p] * kL[w * H_ + n * PH_ + p];
                #pragma unroll
                for (int j = 0; j < 8; ++j)
                    acc += rl[p + 16 * j] * wv[p + 16 * j];
                #pragma unroll
                for (int off = 8; off > 0; off >>= 1)
                    acc += __shfl_down(acc, off, 16);
                if (p == 0) s_sc[n][w] = acc + s_bterm[n];
            }
        }
        __syncthreads();

        // ---- softmax per head (masked), att stored back into s_sc
        {
            int n = t >> 5, lane = t & 31;
            if (cvalid) {
                float m = -INFINITY;
                for (int w = lane; w < wnum; w += 32) m = fmaxf(m, s_sc[n][w]);
                #pragma unroll
                for (int off = 16; off > 0; off >>= 1) m = fmaxf(m, __shfl_xor(m, off, 32));
                float sum = 0.f;
                for (int w = lane; w < wnum; w += 32) sum += expf(s_sc[n][w] - m);
                #pragma unroll
                for (int off = 16; off > 0; off >>= 1) sum += __shfl_xor(sum, off, 32);
                float inv = 1.f / sum;
                for (int w = lane; w < W_; w += 32)
                    s_sc[n][w] = (w < wnum) ? expf(s_sc[n][w] - m) * inv : 0.f;
            } else {
                for (int w = lane; w < W_; w += 32) s_sc[n][w] = 0.f;
            }
        }
        __syncthreads();

        // ---- ctx = att @ v   (split W range between thread halves)
        const float* vL = vbuf + (size_t)(li * B_ + b) * W_ * H_;
        {
            int h = t & 127, n = h >> 4;
            int half = t >> 7;
            float acc = 0.f;
            for (int w = half * 150; w < half * 150 + 150; ++w)
                acc += s_sc[n][w] * vL[w * H_ + h];
            s_tmp[t] = acc;
        }
        __syncthreads();

        // ---- LN1(ctx + x)
        float xln = 0.f;
        if (t < H_) xln = s_tmp[t] + s_tmp[t + 128] + s_x[t];
        float sum1 = block_sum_128(t, xln, s_red);
        float mean1 = sum1 * (1.f / 128.f);
        float d1 = xln - mean1;
        float vs1 = block_sum_128(t, (t < H_) ? d1 * d1 : 0.f, s_red);
        float rstd1 = rsqrtf(vs1 * (1.f / 128.f) + 1e-5f);
        if (t < H_)
            s_x[t] = d1 * rstd1 * ldf<F32>(ln1_g, li * H_ + t) + ldf<F32>(ln1_b, li * H_ + t);
        __syncthreads();

        // ---- FF hidden (each thread 2 units)
        {
            int w1b = li * H_ * FF_;
            int u0 = t * 2;
            float a0 = ldf<F32>(b1, li * FF_ + u0);
            float a1 = ldf<F32>(b1, li * FF_ + u0 + 1);
            for (int j = 0; j < H_; ++j) {
                float x = s_x[j];
                a0 += x * ldf<F32>(W1, w1b + j * FF_ + u0);
                a1 += x * ldf<F32>(W1, w1b + j * FF_ + u0 + 1);
            }
            s_hid[u0] = fmaxf(a0, 0.f);
            s_hid[u0 + 1] = fmaxf(a1, 0.f);
        }
        __syncthreads();

        // ---- FF out + residual + LN2
        float x2 = 0.f;
        if (t < H_) {
            int w2b = li * FF_ * H_;
            float acc = ldf<F32>(b2, li * H_ + t);
            for (int u = 0; u < FF_; ++u)
                acc += s_hid[u] * ldf<F32>(W2, w2b + u * H_ + t);
            x2 = acc + s_x[t];
        }
        float sum2 = block_sum_128(t, x2, s_red);
        float mean2 = sum2 * (1.f / 128.f);
        float d2 = x2 - mean2;
        float vs2 = block_sum_128(t, (t < H_) ? d2 * d2 : 0.f, s_red);
        float rstd2 = rsqrtf(vs2 * (1.f / 128.f) + 1e-5f);
        if (t < H_)
            s_x[t] = d2 * rstd2 * ldf<F32>(ln2_g, li * H_ + t) + ldf<F32>(ln2_b, li * H_ + t);
        __syncthreads();
    }

    // fp32 output — the reference's output dtype
    if (t < H_) out[(b * C_ + c) * H_ + t] = s_x[t];
}

extern "C" void kernel_launch(void* const* d_in, const int* in_sizes, int n_in,
                              void* d_out, int out_size, void* d_ws, size_t ws_size,
                              hipStream_t stream) {
    const void* chars  = d_in[0];
    const void* words  = d_in[1];
    const int* pos_s   = (const int*)d_in[2];
    const int* pos_e   = (const int*)d_in[3];
    const int* lex_s   = (const int*)d_in[4];
    const int* lex_e   = (const int*)d_in[5];
    const int* seq_len = (const int*)d_in[6];
    const int* lex_num = (const int*)d_in[7];
    const void* Wf  = d_in[8];
    const void* bfv = d_in[9];
    const void* Wq  = d_in[10];
    const void* bq  = d_in[11];
    const void* Wk  = d_in[12];
    const void* bk  = d_in[13];
    const void* Wv  = d_in[14];
    const void* bv  = d_in[15];
    const void* Wr  = d_in[16];
    const void* br  = d_in[17];
    const void* u_bias = d_in[18];
    const void* v_bias = d_in[19];
    const void* ln1_g  = d_in[20];
    const void* ln1_b  = d_in[21];
    const void* ln2_g  = d_in[22];
    const void* ln2_b  = d_in[23];
    const void* W1  = d_in[24];
    const void* b1  = d_in[25];
    const void* W2  = d_in[26];
    const void* b2  = d_in[27];

    int*   flag = (int*)d_ws;
    float* PEW  = (float*)((char*)d_ws + 16);      // 4*512*128 = 262144 floats
    float* kbuf = PEW + 4 * PEN_ * H_;             // 307200
    float* vbuf = kbuf + L_ * B_ * W_ * H_;        // 307200

    hipLaunchKernelGGL(detect_kernel, dim3(1), dim3(256), 0, stream,
                       (const unsigned int*)chars, flag);

    hipLaunchKernelGGL((pew_kernel<0>), dim3(PEN_), dim3(H_), 0, stream, flag, Wf, PEW);
    hipLaunchKernelGGL((pew_kernel<1>), dim3(PEN_), dim3(H_), 0, stream, flag, Wf, PEW);

    hipLaunchKernelGGL((kv_kernel<0>), dim3(L_ * B_ * W_), dim3(H_), 0, stream,
                       flag, words, Wk, bk, Wv, bv, kbuf, vbuf);
    hipLaunchKernelGGL((kv_kernel<1>), dim3(L_ * B_ * W_), dim3(H_), 0, stream,
                       flag, words, Wk, bk, Wv, bv, kbuf, vbuf);

    hipLaunchKernelGGL((mega_kernel<0>), dim3(B_ * C_), dim3(256), 0, stream,
                       flag, chars, pos_s, pos_e, lex_s, lex_e, seq_len, lex_num,
                       bfv, Wq, bq, Wr, br, u_bias, v_bias,
                       ln1_g, ln1_b, ln2_g, ln2_b, W1, b1, W2, b2,
                       PEW, kbuf, vbuf, (float*)d_out);
    hipLaunchKernelGGL((mega_kernel<1>), dim3(B_ * C_), dim3(256), 0, stream,
                       flag, chars, pos_s, pos_e, lex_s, lex_e, seq_len, lex_num,
                       bfv, Wq, bq, Wr, br, u_bias, v_bias,
                       ln1_g, ln1_b, ln2_g, ln2_b, W1, b1, W2, b2,
                       PEW, kbuf, vbuf, (float*)d_out);
}

// Round 5
// 397.081 us; speedup vs baseline: 1.8278x; 1.8278x over previous
//
#include <hip/hip_runtime.h>
#include <hip/hip_bf16.h>
#include <math.h>

#define B_ 4
#define C_ 200
#define W_ 300
#define H_ 128
#define NH_ 8
#define PH_ 16
#define FF_ 512
#define L_ 2
#define MAXLEN_ 200
#define PEN_ 512

// Generic float load: F32=1 -> fp32 buffer, F32=0 -> bf16 buffer (bit-exact widen).
template <int F32>
__device__ __forceinline__ float ldf(const void* __restrict__ p, int i) {
    if (F32) return ((const float*)p)[i];
    return __uint_as_float(((unsigned int)((const unsigned short*)p)[i]) << 16);
}

// ---------------- input dtype detector: writes 1 (fp32) or 0 (bf16) to *flag
__global__ void detect_kernel(const unsigned int* __restrict__ chars_raw, int* __restrict__ flag) {
    __shared__ int cnt;
    if (threadIdx.x == 0) cnt = 0;
    __syncthreads();
    int sane = 0;
    for (int i = threadIdx.x; i < 2048; i += 256) {
        unsigned int u = chars_raw[i];
        unsigned int e = (u >> 23) & 0xFFu;
        if (e >= 0x60u && e <= 0x9Fu) sane++;
    }
    atomicAdd(&cnt, sane);
    __syncthreads();
    if (threadIdx.x == 0) *flag = (cnt > 1024) ? 1 : 0;
}

// ---------------- PEW[t][p][h] = sum_j PE[p][j] * Wf[t*128+j][h]
template <int F32>
__global__ void pew_kernel(const int* __restrict__ flag,
                           const void* __restrict__ Wf, float* __restrict__ PEW) {
    if (*flag != F32) return;
    __shared__ float pe[H_];
    int p = blockIdx.x, t = threadIdx.x;  // 128 threads
    {
        int j = (t < 64) ? t : (t - 64);
        double f = exp(-(double)j * (log(10000.0) / 63.0));
        double a = (double)p * f;
        pe[t] = (float)((t < 64) ? sin(a) : cos(a));
    }
    __syncthreads();
    for (int q = 0; q < 4; ++q) {
        float acc = 0.f;
        int base = (q * H_) * H_ + t;
        for (int j = 0; j < H_; ++j)
            acc += pe[j] * ldf<F32>(Wf, base + j * H_);
        PEW[((q * PEN_) + p) * H_ + t] = acc;
    }
}

// ---------------- k/v for both layers: kbuf[((l*B+b)*W+w)*H+h]
template <int F32>
__global__ void kv_kernel(const int* __restrict__ flag,
                          const void* __restrict__ words,
                          const void* __restrict__ Wk, const void* __restrict__ bk,
                          const void* __restrict__ Wv, const void* __restrict__ bv,
                          float* __restrict__ kbuf, float* __restrict__ vbuf) {
    if (*flag != F32) return;
    __shared__ float row[H_];
    int blk = blockIdx.x;                 // l*B*W + b*W + w
    int li = blk / (B_ * W_);
    int rem = blk % (B_ * W_);
    int t = threadIdx.x;                  // 128
    row[t] = ldf<F32>(words, rem * H_ + t);
    __syncthreads();
    int wkb = li * H_ * H_;
    float ak = ldf<F32>(bk, li * H_ + t);
    float av = ldf<F32>(bv, li * H_ + t);
    for (int j = 0; j < H_; ++j) {
        float x = row[j];
        ak += x * ldf<F32>(Wk, wkb + j * H_ + t);
        av += x * ldf<F32>(Wv, wkb + j * H_ + t);
    }
    kbuf[blk * H_ + t] = ak;
    vbuf[blk * H_ + t] = av;
}

// ---------------- block-wide sum of 128 values (t<128 contribute v)
__device__ __forceinline__ float block_sum_128(int t, float v, float* s_red) {
    __syncthreads();
    if (t < 128) s_red[t] = v;
    __syncthreads();
    if (t < 64) {
        float x = s_red[t] + s_red[t + 64];
        #pragma unroll
        for (int off = 32; off > 0; off >>= 1) x += __shfl_down(x, off);
        if (t == 0) s_red[0] = x;
    }
    __syncthreads();
    return s_red[0];
}

// ---------------- mega kernel: one block per (b,c), both layers; fp32 output
template <int F32>
__global__ __launch_bounds__(256) void mega_kernel(
    const int* __restrict__ flag,
    const void* __restrict__ chars,
    const int* __restrict__ pos_s, const int* __restrict__ pos_e,
    const int* __restrict__ lex_s, const int* __restrict__ lex_e,
    const int* __restrict__ seq_len, const int* __restrict__ lex_num,
    const void* __restrict__ bfv,
    const void* __restrict__ Wq, const void* __restrict__ bq,
    const void* __restrict__ Wr, const void* __restrict__ br,
    const void* __restrict__ u_bias, const void* __restrict__ v_bias,
    const void* __restrict__ ln1_g, const void* __restrict__ ln1_b,
    const void* __restrict__ ln2_g, const void* __restrict__ ln2_b,
    const void* __restrict__ W1, const void* __restrict__ b1,
    const void* __restrict__ W2, const void* __restrict__ b2,
    const float* __restrict__ PEW, const float* __restrict__ kbuf, const float* __restrict__ vbuf,
    float* __restrict__ out) {
    if (*flag != F32) return;

    __shared__ float s_x[H_], s_qu[H_], s_qv[H_], s_bf[H_];
    __shared__ float s_wvec[NH_][H_];
    __shared__ float s_bterm[NH_];
    __shared__ float s_sc[NH_][W_];
    __shared__ float s_rel[32 * 129];      // [w_local][h], pad 129: conflict-free dot reads
    __shared__ float s_red[H_];
    __shared__ float s_hid[FF_];
    __shared__ float s_tmp[256];
    __shared__ int s_ls[W_], s_le[W_];

    int blk = blockIdx.x;
    int b = blk / C_, c = blk % C_;
    int t = threadIdx.x;

    if (t < H_) {
        s_x[t] = ldf<F32>(chars, (b * C_ + c) * H_ + t);
        s_bf[t] = ldf<F32>(bfv, t);
    }
    for (int w = t; w < W_; w += 256) {
        s_ls[w] = lex_s[b * W_ + w];
        s_le[w] = lex_e[b * W_ + w];
    }
    int ps = pos_s[b * C_ + c];
    int pev = pos_e[b * C_ + c];
    int cvalid = (c < seq_len[b]);
    int wnum = lex_num[b];
    __syncthreads();

    for (int li = 0; li < L_; ++li) {
        // ---- q projection (+u, +v bias variants)
        if (t < H_) {
            int wqb = li * H_ * H_;
            float acc = ldf<F32>(bq, li * H_ + t);
            for (int j = 0; j < H_; ++j)
                acc += s_x[j] * ldf<F32>(Wq, wqb + j * H_ + t);
            s_qu[t] = acc + ldf<F32>(u_bias, li * H_ + t);
            s_qv[t] = acc + ldf<F32>(v_bias, li * H_ + t);
        }
        __syncthreads();

        // ---- wvec[n][h] = sum_p Wr[h][n*16+p]*qv[n*16+p];  bterm[n] = sum_p br[n*16+p]*qv
        if (t < H_) {
            int wrb = li * H_ * H_ + t * H_;
            for (int n = 0; n < NH_; ++n) {
                float acc = 0.f;
                #pragma unroll
                for (int p = 0; p < PH_; ++p)
                    acc += ldf<F32>(Wr, wrb + n * PH_ + p) * s_qv[n * PH_ + p];
                s_wvec[n][t] = acc;
            }
        } else if (t < H_ + NH_) {
            int n = t - H_;
            float acc = 0.f;
            #pragma unroll
            for (int p = 0; p < PH_; ++p)
                acc += ldf<F32>(br, li * H_ + n * PH_ + p) * s_qv[n * PH_ + p];
            s_bterm[n] = acc;
        }
        __syncthreads();

        // ---- score loop: tiles of 32 w's, 2 barriers per tile (10 tiles)
        const float* kL = kbuf + (size_t)(li * B_ + b) * W_ * H_;
        for (int w0 = 0; w0 < W_; w0 += 32) {
            // build rel tile: thread t -> w_local = t>>3, h = (t&7)*16 .. +15
            {
                int wl = t >> 3;
                int h0 = (t & 7) * 16;
                int w = w0 + wl;
                if (w < W_) {
                    int ls = s_ls[w], le = s_le[w];
                    int i0 = min(max(ps - ls + MAXLEN_, 0), PEN_ - 1);
                    int i1 = min(max(ps - le + MAXLEN_, 0), PEN_ - 1);
                    int i2 = min(max(pev - ls + MAXLEN_, 0), PEN_ - 1);
                    int i3 = min(max(pev - le + MAXLEN_, 0), PEN_ - 1);
                    const float* p0 = PEW + (0 * PEN_ + i0) * H_;
                    const float* p1 = PEW + (1 * PEN_ + i1) * H_;
                    const float* p2 = PEW + (2 * PEN_ + i2) * H_;
                    const float* p3 = PEW + (3 * PEN_ + i3) * H_;
                    #pragma unroll
                    for (int r = 0; r < 16; ++r) {
                        int h = h0 + r;
                        float rv = s_bf[h] + p0[h] + p1[h] + p2[h] + p3[h];
                        s_rel[wl * 129 + h] = fmaxf(rv, 0.f);
                    }
                }
            }
            __syncthreads();
            // score: thread t -> n = t>>5, w_local = t&31; full serial dot (no shuffles)
            {
                int n = t >> 5, wl = t & 31, w = w0 + wl;
                if (w < W_) {
                    float acc = s_bterm[n];
                    const float* kr = kL + (size_t)w * H_ + n * PH_;
                    #pragma unroll
                    for (int p = 0; p < PH_; ++p) acc += s_qu[n * PH_ + p] * kr[p];
                    const float* rl = s_rel + wl * 129;
                    const float* wv = s_wvec[n];
                    for (int h = 0; h < H_; ++h) acc += rl[h] * wv[h];
                    s_sc[n][w] = acc;
                }
            }
            __syncthreads();
        }

        // ---- softmax per head (masked), att stored back into s_sc
        {
            int n = t >> 5, lane = t & 31;
            if (cvalid) {
                float m = -INFINITY;
                for (int w = lane; w < wnum; w += 32) m = fmaxf(m, s_sc[n][w]);
                #pragma unroll
                for (int off = 16; off > 0; off >>= 1) m = fmaxf(m, __shfl_xor(m, off, 32));
                float sum = 0.f;
                for (int w = lane; w < wnum; w += 32) sum += expf(s_sc[n][w] - m);
                #pragma unroll
                for (int off = 16; off > 0; off >>= 1) sum += __shfl_xor(sum, off, 32);
                float inv = 1.f / sum;
                for (int w = lane; w < W_; w += 32)
                    s_sc[n][w] = (w < wnum) ? expf(s_sc[n][w] - m) * inv : 0.f;
            } else {
                for (int w = lane; w < W_; w += 32) s_sc[n][w] = 0.f;
            }
        }
        __syncthreads();

        // ---- ctx = att @ v   (split W range between thread halves)
        const float* vL = vbuf + (size_t)(li * B_ + b) * W_ * H_;
        {
            int h = t & 127, n = h >> 4;
            int half = t >> 7;
            float acc = 0.f;
            for (int w = half * 150; w < half * 150 + 150; ++w)
                acc += s_sc[n][w] * vL[w * H_ + h];
            s_tmp[t] = acc;
        }
        __syncthreads();

        // ---- LN1(ctx + x)
        float xln = 0.f;
        if (t < H_) xln = s_tmp[t] + s_tmp[t + 128] + s_x[t];
        float sum1 = block_sum_128(t, xln, s_red);
        float mean1 = sum1 * (1.f / 128.f);
        float d1 = xln - mean1;
        float vs1 = block_sum_128(t, (t < H_) ? d1 * d1 : 0.f, s_red);
        float rstd1 = rsqrtf(vs1 * (1.f / 128.f) + 1e-5f);
        if (t < H_)
            s_x[t] = d1 * rstd1 * ldf<F32>(ln1_g, li * H_ + t) + ldf<F32>(ln1_b, li * H_ + t);
        __syncthreads();

        // ---- FF hidden (each thread 2 units)
        {
            int w1b = li * H_ * FF_;
            int u0 = t * 2;
            float a0 = ldf<F32>(b1, li * FF_ + u0);
            float a1 = ldf<F32>(b1, li * FF_ + u0 + 1);
            for (int j = 0; j < H_; ++j) {
                float x = s_x[j];
                a0 += x * ldf<F32>(W1, w1b + j * FF_ + u0);
                a1 += x * ldf<F32>(W1, w1b + j * FF_ + u0 + 1);
            }
            s_hid[u0] = fmaxf(a0, 0.f);
            s_hid[u0 + 1] = fmaxf(a1, 0.f);
        }
        __syncthreads();

        // ---- FF out + residual + LN2
        float x2 = 0.f;
        if (t < H_) {
            int w2b = li * FF_ * H_;
            float acc = ldf<F32>(b2, li * H_ + t);
            for (int u = 0; u < FF_; ++u)
                acc += s_hid[u] * ldf<F32>(W2, w2b + u * H_ + t);
            x2 = acc + s_x[t];
        }
        float sum2 = block_sum_128(t, x2, s_red);
        float mean2 = sum2 * (1.f / 128.f);
        float d2 = x2 - mean2;
        float vs2 = block_sum_128(t, (t < H_) ? d2 * d2 : 0.f, s_red);
        float rstd2 = rsqrtf(vs2 * (1.f / 128.f) + 1e-5f);
        if (t < H_)
            s_x[t] = d2 * rstd2 * ldf<F32>(ln2_g, li * H_ + t) + ldf<F32>(ln2_b, li * H_ + t);
        __syncthreads();
    }

    // fp32 output — the reference's output dtype
    if (t < H_) out[(b * C_ + c) * H_ + t] = s_x[t];
}

extern "C" void kernel_launch(void* const* d_in, const int* in_sizes, int n_in,
                              void* d_out, int out_size, void* d_ws, size_t ws_size,
                              hipStream_t stream) {
    const void* chars  = d_in[0];
    const void* words  = d_in[1];
    const int* pos_s   = (const int*)d_in[2];
    const int* pos_e   = (const int*)d_in[3];
    const int* lex_s   = (const int*)d_in[4];
    const int* lex_e   = (const int*)d_in[5];
    const int* seq_len = (const int*)d_in[6];
    const int* lex_num = (const int*)d_in[7];
    const void* Wf  = d_in[8];
    const void* bfv = d_in[9];
    const void* Wq  = d_in[10];
    const void* bq  = d_in[11];
    const void* Wk  = d_in[12];
    const void* bk  = d_in[13];
    const void* Wv  = d_in[14];
    const void* bv  = d_in[15];
    const void* Wr  = d_in[16];
    const void* br  = d_in[17];
    const void* u_bias = d_in[18];
    const void* v_bias = d_in[19];
    const void* ln1_g  = d_in[20];
    const void* ln1_b  = d_in[21];
    const void* ln2_g  = d_in[22];
    const void* ln2_b  = d_in[23];
    const void* W1  = d_in[24];
    const void* b1  = d_in[25];
    const void* W2  = d_in[26];
    const void* b2  = d_in[27];

    int*   flag = (int*)d_ws;
    float* PEW  = (float*)((char*)d_ws + 16);      // 4*512*128 = 262144 floats
    float* kbuf = PEW + 4 * PEN_ * H_;             // 307200
    float* vbuf = kbuf + L_ * B_ * W_ * H_;        // 307200

    hipLaunchKernelGGL(detect_kernel, dim3(1), dim3(256), 0, stream,
                       (const unsigned int*)chars, flag);

    hipLaunchKernelGGL((pew_kernel<0>), dim3(PEN_), dim3(H_), 0, stream, flag, Wf, PEW);
    hipLaunchKernelGGL((pew_kernel<1>), dim3(PEN_), dim3(H_), 0, stream, flag, Wf, PEW);

    hipLaunchKernelGGL((kv_kernel<0>), dim3(L_ * B_ * W_), dim3(H_), 0, stream,
                       flag, words, Wk, bk, Wv, bv, kbuf, vbuf);
    hipLaunchKernelGGL((kv_kernel<1>), dim3(L_ * B_ * W_), dim3(H_), 0, stream,
                       flag, words, Wk, bk, Wv, bv, kbuf, vbuf);

    hipLaunchKernelGGL((mega_kernel<0>), dim3(B_ * C_), dim3(256), 0, stream,
                       flag, chars, pos_s, pos_e, lex_s, lex_e, seq_len, lex_num,
                       bfv, Wq, bq, Wr, br, u_bias, v_bias,
                       ln1_g, ln1_b, ln2_g, ln2_b, W1, b1, W2, b2,
                       PEW, kbuf, vbuf, (float*)d_out);
    hipLaunchKernelGGL((mega_kernel<1>), dim3(B_ * C_), dim3(256), 0, stream,
                       flag, chars, pos_s, pos_e, lex_s, lex_e, seq_len, lex_num,
                       bfv, Wq, bq, Wr, br, u_bias, v_bias,
                       ln1_g, ln1_b, ln2_g, ln2_b, W1, b1, W2, b2,
                       PEW, kbuf, vbuf, (float*)d_out);
}

// Round 6
// 393.129 us; speedup vs baseline: 1.8461x; 1.0101x over previous
//
#include <hip/hip_runtime.h>
#include <math.h>

#define B_ 4
#define C_ 200
#define W_ 300
#define H_ 128
#define NH_ 8
#define PH_ 16
#define FF_ 512
#define L_ 2
#define MAXLEN_ 200
#define PEN_ 512

// ---------------- prep: blocks [0,512) build PEW; blocks [512, 512+2400) build k/v
// PEW[q][p][h] = sum_j PE[p][j] * Wf[q*128+j][h]
// kbuf[((l*B+b)*W+w)*H+h], vbuf likewise
__global__ __launch_bounds__(128) void prep_kernel(
        const float* __restrict__ Wf,
        const float* __restrict__ words,
        const float* __restrict__ Wk, const float* __restrict__ bk,
        const float* __restrict__ Wv, const float* __restrict__ bv,
        float* __restrict__ PEW, float* __restrict__ kbuf, float* __restrict__ vbuf) {
    __shared__ __align__(16) float s_row[H_];
    int t = threadIdx.x;
    if (blockIdx.x < PEN_) {
        int p = blockIdx.x;
        {
            int j = (t < 64) ? t : (t - 64);
            double f = exp(-(double)j * (log(10000.0) / 63.0));
            double a = (double)p * f;
            s_row[t] = (float)((t < 64) ? sin(a) : cos(a));
        }
        __syncthreads();
        const float4* pe4 = (const float4*)s_row;
        float4 acc0 = {0,0,0,0}, acc1 = {0,0,0,0}, acc2 = {0,0,0,0}, acc3 = {0,0,0,0};
        for (int g = 0; g < 32; ++g) {
            float4 x = pe4[g];
            int j0 = 4 * g;
            #pragma unroll
            for (int k = 0; k < 4; ++k) {
                float xv = (k == 0) ? x.x : (k == 1) ? x.y : (k == 2) ? x.z : x.w;
                int row = (j0 + k) * H_ + t;
                acc0.x += xv * Wf[0 * H_ * H_ + row];  // table 0 uses acc0.x etc: keep 4 indep chains per table
                acc1.x += xv * Wf[1 * H_ * H_ + row];
                acc2.x += xv * Wf[2 * H_ * H_ + row];
                acc3.x += xv * Wf[3 * H_ * H_ + row];
            }
        }
        PEW[(0 * PEN_ + p) * H_ + t] = acc0.x;
        PEW[(1 * PEN_ + p) * H_ + t] = acc1.x;
        PEW[(2 * PEN_ + p) * H_ + t] = acc2.x;
        PEW[(3 * PEN_ + p) * H_ + t] = acc3.x;
    } else {
        int blk = blockIdx.x - PEN_;          // l*B*W + b*W + w
        int li = blk / (B_ * W_);
        int rem = blk % (B_ * W_);
        s_row[t] = words[rem * H_ + t];
        __syncthreads();
        const float4* row4 = (const float4*)s_row;
        const float* wk = Wk + li * H_ * H_;
        const float* wv = Wv + li * H_ * H_;
        float4 ak = {0,0,0,0}, av = {0,0,0,0};
        for (int g = 0; g < 32; ++g) {
            float4 x = row4[g];
            int j0 = 4 * g;
            ak.x += x.x * wk[(j0 + 0) * H_ + t];
            ak.y += x.y * wk[(j0 + 1) * H_ + t];
            ak.z += x.z * wk[(j0 + 2) * H_ + t];
            ak.w += x.w * wk[(j0 + 3) * H_ + t];
            av.x += x.x * wv[(j0 + 0) * H_ + t];
            av.y += x.y * wv[(j0 + 1) * H_ + t];
            av.z += x.z * wv[(j0 + 2) * H_ + t];
            av.w += x.w * wv[(j0 + 3) * H_ + t];
        }
        kbuf[blk * H_ + t] = (ak.x + ak.y) + (ak.z + ak.w) + bk[li * H_ + t];
        vbuf[blk * H_ + t] = (av.x + av.y) + (av.z + av.w) + bv[li * H_ + t];
    }
}

// ---------------- block-wide sum of 128 values (t<128 contribute v)
__device__ __forceinline__ float block_sum_128(int t, float v, float* s_red) {
    __syncthreads();
    if (t < 128) s_red[t] = v;
    __syncthreads();
    if (t < 64) {
        float x = s_red[t] + s_red[t + 64];
        #pragma unroll
        for (int off = 32; off > 0; off >>= 1) x += __shfl_down(x, off);
        if (t == 0) s_red[0] = x;
    }
    __syncthreads();
    return s_red[0];
}

// ---------------- mega kernel: one block per (b,c), both layers; fp32 in/out
__global__ __launch_bounds__(256) void mega_kernel(
    const float* __restrict__ chars,
    const int* __restrict__ pos_s, const int* __restrict__ pos_e,
    const int* __restrict__ lex_s, const int* __restrict__ lex_e,
    const int* __restrict__ seq_len, const int* __restrict__ lex_num,
    const float* __restrict__ bfv,
    const float* __restrict__ Wq, const float* __restrict__ bq,
    const float* __restrict__ Wr, const float* __restrict__ br,
    const float* __restrict__ u_bias, const float* __restrict__ v_bias,
    const float* __restrict__ ln1_g, const float* __restrict__ ln1_b,
    const float* __restrict__ ln2_g, const float* __restrict__ ln2_b,
    const float* __restrict__ W1, const float* __restrict__ b1,
    const float* __restrict__ W2, const float* __restrict__ b2,
    const float* __restrict__ PEW, const float* __restrict__ kbuf, const float* __restrict__ vbuf,
    float* __restrict__ out) {

    __shared__ __align__(16) float s_x[H_], s_qu[H_], s_qv[H_], s_bf[H_];
    __shared__ __align__(16) float s_wvec[NH_][H_];
    __shared__ float s_bterm[NH_];
    __shared__ __align__(16) float s_sc[NH_][W_];
    __shared__ __align__(16) float s_rel[32 * 132];   // [w_local][h], pad 132 (33 float4)
    __shared__ float s_red[H_];
    __shared__ __align__(16) float s_hid[FF_];
    __shared__ float s_tmp[256];
    __shared__ int s_ls[W_], s_le[W_];

    int blk = blockIdx.x;
    int b = blk / C_, c = blk % C_;
    int t = threadIdx.x;

    if (t < H_) {
        s_x[t] = chars[(b * C_ + c) * H_ + t];
        s_bf[t] = bfv[t];
    }
    for (int w = t; w < W_; w += 256) {
        s_ls[w] = lex_s[b * W_ + w];
        s_le[w] = lex_e[b * W_ + w];
    }
    int ps = pos_s[b * C_ + c];
    int pev = pos_e[b * C_ + c];
    int cvalid = (c < seq_len[b]);
    int wnum = lex_num[b];
    __syncthreads();

    for (int li = 0; li < L_; ++li) {
        // ---- q projection (+u, +v bias variants); t<128, float4 x, 4-lane acc
        if (t < H_) {
            const float* WqL = Wq + li * H_ * H_;
            const float4* x4 = (const float4*)s_x;
            float4 a4 = {0,0,0,0};
            for (int g = 0; g < 32; ++g) {
                float4 x = x4[g];
                int j0 = 4 * g;
                a4.x += x.x * WqL[(j0 + 0) * H_ + t];
                a4.y += x.y * WqL[(j0 + 1) * H_ + t];
                a4.z += x.z * WqL[(j0 + 2) * H_ + t];
                a4.w += x.w * WqL[(j0 + 3) * H_ + t];
            }
            float acc = (a4.x + a4.y) + (a4.z + a4.w) + bq[li * H_ + t];
            s_qu[t] = acc + u_bias[li * H_ + t];
            s_qv[t] = acc + v_bias[li * H_ + t];
        }
        __syncthreads();

        // ---- wvec[n][h] = sum_p Wr[h][n*16+p]*qv[n*16+p];  bterm[n] = br[n*16..]·qv
        if (t < H_) {
            const float* WrRow = Wr + li * H_ * H_ + t * H_;
            for (int n = 0; n < NH_; ++n) {
                const float4* wr4 = (const float4*)(WrRow + n * PH_);
                const float4* qv4 = (const float4*)(s_qv + n * PH_);
                float4 a4 = {0,0,0,0};
                #pragma unroll
                for (int i = 0; i < 4; ++i) {
                    float4 wv_ = wr4[i], qv_ = qv4[i];
                    a4.x += wv_.x * qv_.x; a4.y += wv_.y * qv_.y;
                    a4.z += wv_.z * qv_.z; a4.w += wv_.w * qv_.w;
                }
                s_wvec[n][t] = (a4.x + a4.y) + (a4.z + a4.w);
            }
        } else if (t < H_ + NH_) {
            int n = t - H_;
            const float4* br4 = (const float4*)(br + li * H_ + n * PH_);
            const float4* qv4 = (const float4*)(s_qv + n * PH_);
            float4 a4 = {0,0,0,0};
            #pragma unroll
            for (int i = 0; i < 4; ++i) {
                float4 wv_ = br4[i], qv_ = qv4[i];
                a4.x += wv_.x * qv_.x; a4.y += wv_.y * qv_.y;
                a4.z += wv_.z * qv_.z; a4.w += wv_.w * qv_.w;
            }
            s_bterm[n] = (a4.x + a4.y) + (a4.z + a4.w);
        }
        __syncthreads();

        // ---- score loop: tiles of 32 w's
        const float* kL = kbuf + (size_t)(li * B_ + b) * W_ * H_;
        for (int w0 = 0; w0 < W_; w0 += 32) {
            // rel build: t -> wl = t>>3 (8 lanes/w), chunk = t&7 (16 h each); float4 ops
            {
                int wl = t >> 3;
                int h0 = (t & 7) * 16;
                int w = w0 + wl;
                if (w < W_) {
                    int ls = s_ls[w], le = s_le[w];
                    int i0 = min(max(ps - ls + MAXLEN_, 0), PEN_ - 1);
                    int i1 = min(max(ps - le + MAXLEN_, 0), PEN_ - 1);
                    int i2 = min(max(pev - ls + MAXLEN_, 0), PEN_ - 1);
                    int i3 = min(max(pev - le + MAXLEN_, 0), PEN_ - 1);
                    const float4* p0 = (const float4*)(PEW + (0 * PEN_ + i0) * H_ + h0);
                    const float4* p1 = (const float4*)(PEW + (1 * PEN_ + i1) * H_ + h0);
                    const float4* p2 = (const float4*)(PEW + (2 * PEN_ + i2) * H_ + h0);
                    const float4* p3 = (const float4*)(PEW + (3 * PEN_ + i3) * H_ + h0);
                    const float4* bf4 = (const float4*)(s_bf + h0);
                    float4* dst = (float4*)(s_rel + wl * 132 + h0);
                    #pragma unroll
                    for (int i = 0; i < 4; ++i) {
                        float4 a = p0[i], bq4 = p1[i], cq = p2[i], dq = p3[i], e = bf4[i];
                        float4 r;
                        r.x = fmaxf(e.x + a.x + bq4.x + cq.x + dq.x, 0.f);
                        r.y = fmaxf(e.y + a.y + bq4.y + cq.y + dq.y, 0.f);
                        r.z = fmaxf(e.z + a.z + bq4.z + cq.z + dq.z, 0.f);
                        r.w = fmaxf(e.w + a.w + bq4.w + cq.w + dq.w, 0.f);
                        dst[i] = r;
                    }
                }
            }
            __syncthreads();
            // score: t -> n = t>>5, wl = t&31; float4 dot, 4 indep chains
            {
                int n = t >> 5, wl = t & 31, w = w0 + wl;
                if (w < W_) {
                    float4 a4 = {0,0,0,0};
                    const float4* qu4 = (const float4*)(s_qu + n * PH_);
                    const float4* kr4 = (const float4*)(kL + (size_t)w * H_ + n * PH_);
                    #pragma unroll
                    for (int i = 0; i < 4; ++i) {
                        float4 q = qu4[i], k = kr4[i];
                        a4.x += q.x * k.x; a4.y += q.y * k.y;
                        a4.z += q.z * k.z; a4.w += q.w * k.w;
                    }
                    const float4* rl4 = (const float4*)(s_rel + wl * 132);
                    const float4* wv4 = (const float4*)(s_wvec[n]);
                    for (int i = 0; i < 32; ++i) {
                        float4 r = rl4[i], v = wv4[i];
                        a4.x += r.x * v.x; a4.y += r.y * v.y;
                        a4.z += r.z * v.z; a4.w += r.w * v.w;
                    }
                    s_sc[n][w] = (a4.x + a4.y) + (a4.z + a4.w) + s_bterm[n];
                }
            }
            __syncthreads();
        }

        // ---- softmax per head (masked), att stored back into s_sc
        {
            int n = t >> 5, lane = t & 31;
            if (cvalid) {
                float m = -INFINITY;
                for (int w = lane; w < wnum; w += 32) m = fmaxf(m, s_sc[n][w]);
                #pragma unroll
                for (int off = 16; off > 0; off >>= 1) m = fmaxf(m, __shfl_xor(m, off, 32));
                float sum = 0.f;
                for (int w = lane; w < wnum; w += 32) sum += expf(s_sc[n][w] - m);
                #pragma unroll
                for (int off = 16; off > 0; off >>= 1) sum += __shfl_xor(sum, off, 32);
                float inv = 1.f / sum;
                for (int w = lane; w < W_; w += 32)
                    s_sc[n][w] = (w < wnum) ? expf(s_sc[n][w] - m) * inv : 0.f;
            } else {
                for (int w = lane; w < W_; w += 32) s_sc[n][w] = 0.f;
            }
        }
        __syncthreads();

        // ---- ctx = att @ v; halves split W as [0,152) / [152,300); float4 att
        const float* vL = vbuf + (size_t)(li * B_ + b) * W_ * H_;
        {
            int h = t & 127, n = h >> 4;
            int half = t >> 7;
            int g0 = half ? 38 : 0, g1 = half ? 75 : 38;   // float4 group range
            const float4* att4 = (const float4*)(s_sc[n]);
            float4 a4 = {0,0,0,0};
            for (int g = g0; g < g1; ++g) {
                float4 a = att4[g];
                int w = 4 * g;
                a4.x += a.x * vL[(size_t)(w + 0) * H_ + h];
                a4.y += a.y * vL[(size_t)(w + 1) * H_ + h];
                a4.z += a.z * vL[(size_t)(w + 2) * H_ + h];
                a4.w += a.w * vL[(size_t)(w + 3) * H_ + h];
            }
            s_tmp[t] = (a4.x + a4.y) + (a4.z + a4.w);
        }
        __syncthreads();

        // ---- LN1(ctx + x)
        float xln = 0.f;
        if (t < H_) xln = s_tmp[t] + s_tmp[t + 128] + s_x[t];
        float sum1 = block_sum_128(t, xln, s_red);
        float mean1 = sum1 * (1.f / 128.f);
        float d1 = xln - mean1;
        float vs1 = block_sum_128(t, (t < H_) ? d1 * d1 : 0.f, s_red);
        float rstd1 = rsqrtf(vs1 * (1.f / 128.f) + 1e-5f);
        if (t < H_)
            s_x[t] = d1 * rstd1 * ln1_g[li * H_ + t] + ln1_b[li * H_ + t];
        __syncthreads();

        // ---- FF hidden: thread t -> units (2t, 2t+1); float2 weight loads
        {
            const float* W1L = W1 + li * H_ * FF_;
            int u0 = t * 2;
            const float4* x4 = (const float4*)s_x;
            float4 a04 = {0,0,0,0}, a14 = {0,0,0,0};
            for (int g = 0; g < 32; ++g) {
                float4 x = x4[g];
                int j0 = 4 * g;
                float2 w0_ = *(const float2*)(W1L + (j0 + 0) * FF_ + u0);
                float2 w1_ = *(const float2*)(W1L + (j0 + 1) * FF_ + u0);
                float2 w2_ = *(const float2*)(W1L + (j0 + 2) * FF_ + u0);
                float2 w3_ = *(const float2*)(W1L + (j0 + 3) * FF_ + u0);
                a04.x += x.x * w0_.x; a14.x += x.x * w0_.y;
                a04.y += x.y * w1_.x; a14.y += x.y * w1_.y;
                a04.z += x.z * w2_.x; a14.z += x.z * w2_.y;
                a04.w += x.w * w3_.x; a14.w += x.w * w3_.y;
            }
            float a0 = (a04.x + a04.y) + (a04.z + a04.w) + b1[li * FF_ + u0];
            float a1 = (a14.x + a14.y) + (a14.z + a14.w) + b1[li * FF_ + u0 + 1];
            s_hid[u0] = fmaxf(a0, 0.f);
            s_hid[u0 + 1] = fmaxf(a1, 0.f);
        }
        __syncthreads();

        // ---- FF out + residual + LN2; t<128, float4 hid
        float x2 = 0.f;
        if (t < H_) {
            const float* W2L = W2 + li * FF_ * H_;
            const float4* h4 = (const float4*)s_hid;
            float4 a4 = {0,0,0,0};
            for (int g = 0; g < 128; ++g) {
                float4 hh = h4[g];
                int u = 4 * g;
                a4.x += hh.x * W2L[(u + 0) * H_ + t];
                a4.y += hh.y * W2L[(u + 1) * H_ + t];
                a4.z += hh.z * W2L[(u + 2) * H_ + t];
                a4.w += hh.w * W2L[(u + 3) * H_ + t];
            }
            x2 = (a4.x + a4.y) + (a4.z + a4.w) + b2[li * H_ + t] + s_x[t];
        }
        float sum2 = block_sum_128(t, x2, s_red);
        float mean2 = sum2 * (1.f / 128.f);
        float d2 = x2 - mean2;
        float vs2 = block_sum_128(t, (t < H_) ? d2 * d2 : 0.f, s_red);
        float rstd2 = rsqrtf(vs2 * (1.f / 128.f) + 1e-5f);
        if (t < H_)
            s_x[t] = d2 * rstd2 * ln2_g[li * H_ + t] + ln2_b[li * H_ + t];
        __syncthreads();
    }

    if (t < H_) out[(b * C_ + c) * H_ + t] = s_x[t];
}

extern "C" void kernel_launch(void* const* d_in, const int* in_sizes, int n_in,
                              void* d_out, int out_size, void* d_ws, size_t ws_size,
                              hipStream_t stream) {
    const float* chars  = (const float*)d_in[0];
    const float* words  = (const float*)d_in[1];
    const int* pos_s   = (const int*)d_in[2];
    const int* pos_e   = (const int*)d_in[3];
    const int* lex_s   = (const int*)d_in[4];
    const int* lex_e   = (const int*)d_in[5];
    const int* seq_len = (const int*)d_in[6];
    const int* lex_num = (const int*)d_in[7];
    const float* Wf  = (const float*)d_in[8];
    const float* bfv = (const float*)d_in[9];
    const float* Wq  = (const float*)d_in[10];
    const float* bq  = (const float*)d_in[11];
    const float* Wk  = (const float*)d_in[12];
    const float* bk  = (const float*)d_in[13];
    const float* Wv  = (const float*)d_in[14];
    const float* bv  = (const float*)d_in[15];
    const float* Wr  = (const float*)d_in[16];
    const float* br  = (const float*)d_in[17];
    const float* u_bias = (const float*)d_in[18];
    const float* v_bias = (const float*)d_in[19];
    const float* ln1_g  = (const float*)d_in[20];
    const float* ln1_b  = (const float*)d_in[21];
    const float* ln2_g  = (const float*)d_in[22];
    const float* ln2_b  = (const float*)d_in[23];
    const float* W1  = (const float*)d_in[24];
    const float* b1  = (const float*)d_in[25];
    const float* W2  = (const float*)d_in[26];
    const float* b2  = (const float*)d_in[27];

    float* PEW  = (float*)d_ws;                    // 4*512*128 = 262144 floats
    float* kbuf = PEW + 4 * PEN_ * H_;             // 307200
    float* vbuf = kbuf + L_ * B_ * W_ * H_;        // 307200

    prep_kernel<<<dim3(PEN_ + L_ * B_ * W_), dim3(128), 0, stream>>>(
        Wf, words, Wk, bk, Wv, bv, PEW, kbuf, vbuf);

    mega_kernel<<<dim3(B_ * C_), dim3(256), 0, stream>>>(
        chars, pos_s, pos_e, lex_s, lex_e, seq_len, lex_num,
        bfv, Wq, bq, Wr, br, u_bias, v_bias,
        ln1_g, ln1_b, ln2_g, ln2_b, W1, b1, W2, b2,
        PEW, kbuf, vbuf, (float*)d_out);
}

// Round 7
// 372.880 us; speedup vs baseline: 1.9464x; 1.0543x over previous
//
#include <hip/hip_runtime.h>
#include <math.h>

#define B_ 4
#define C_ 200
#define W_ 300
#define H_ 128
#define NH_ 8
#define PH_ 16
#define FF_ 512
#define L_ 2
#define MAXLEN_ 200
#define PEN_ 512

typedef __bf16 bf16x8 __attribute__((ext_vector_type(8)));
typedef float f32x4v __attribute__((ext_vector_type(4)));

// ---------------- prep: blocks [0,512) build PEW (bf folded into table 0);
// blocks [512, 512+2400) build k/v.  PEW[q][p][h] = sum_j PE[p][j]*Wf[q*128+j][h] (+bf[h] for q=0)
__global__ __launch_bounds__(128) void prep_kernel(
        const float* __restrict__ Wf, const float* __restrict__ bfv,
        const float* __restrict__ words,
        const float* __restrict__ Wk, const float* __restrict__ bk,
        const float* __restrict__ Wv, const float* __restrict__ bv,
        float* __restrict__ PEW, float* __restrict__ kbuf, float* __restrict__ vbuf) {
    __shared__ __align__(16) float s_row[H_];
    int t = threadIdx.x;
    if (blockIdx.x < PEN_) {
        int p = blockIdx.x;
        {
            int j = (t < 64) ? t : (t - 64);
            double f = exp(-(double)j * (log(10000.0) / 63.0));
            double a = (double)p * f;
            s_row[t] = (float)((t < 64) ? sin(a) : cos(a));
        }
        __syncthreads();
        float acc0 = 0.f, acc1 = 0.f, acc2 = 0.f, acc3 = 0.f;
        for (int j = 0; j < H_; ++j) {
            float xv = s_row[j];
            int row = j * H_ + t;
            acc0 += xv * Wf[0 * H_ * H_ + row];
            acc1 += xv * Wf[1 * H_ * H_ + row];
            acc2 += xv * Wf[2 * H_ * H_ + row];
            acc3 += xv * Wf[3 * H_ * H_ + row];
        }
        PEW[(0 * PEN_ + p) * H_ + t] = acc0 + bfv[t];   // fold bias into table 0
        PEW[(1 * PEN_ + p) * H_ + t] = acc1;
        PEW[(2 * PEN_ + p) * H_ + t] = acc2;
        PEW[(3 * PEN_ + p) * H_ + t] = acc3;
    } else {
        int blk = blockIdx.x - PEN_;          // l*B*W + b*W + w
        int li = blk / (B_ * W_);
        int rem = blk % (B_ * W_);
        s_row[t] = words[rem * H_ + t];
        __syncthreads();
        const float4* row4 = (const float4*)s_row;
        const float* wk = Wk + li * H_ * H_;
        const float* wv = Wv + li * H_ * H_;
        float4 ak = {0,0,0,0}, av = {0,0,0,0};
        for (int g = 0; g < 32; ++g) {
            float4 x = row4[g];
            int j0 = 4 * g;
            ak.x += x.x * wk[(j0 + 0) * H_ + t];
            ak.y += x.y * wk[(j0 + 1) * H_ + t];
            ak.z += x.z * wk[(j0 + 2) * H_ + t];
            ak.w += x.w * wk[(j0 + 3) * H_ + t];
            av.x += x.x * wv[(j0 + 0) * H_ + t];
            av.y += x.y * wv[(j0 + 1) * H_ + t];
            av.z += x.z * wv[(j0 + 2) * H_ + t];
            av.w += x.w * wv[(j0 + 3) * H_ + t];
        }
        kbuf[blk * H_ + t] = (ak.x + ak.y) + (ak.z + ak.w) + bk[li * H_ + t];
        vbuf[blk * H_ + t] = (av.x + av.y) + (av.z + av.w) + bv[li * H_ + t];
    }
}

// ---------------- block-wide sum of 128 values (t<128 contribute v)
__device__ __forceinline__ float block_sum_128(int t, float v, float* s_red) {
    __syncthreads();
    if (t < 128) s_red[t] = v;
    __syncthreads();
    if (t < 64) {
        float x = s_red[t] + s_red[t + 64];
        #pragma unroll
        for (int off = 32; off > 0; off >>= 1) x += __shfl_down(x, off);
        if (t == 0) s_red[0] = x;
    }
    __syncthreads();
    return s_red[0];
}

// ---------------- mega kernel: one block per (b,c), both layers; fp32 in/out
__global__ __launch_bounds__(256) void mega_kernel(
    const float* __restrict__ chars,
    const int* __restrict__ pos_s, const int* __restrict__ pos_e,
    const int* __restrict__ lex_s, const int* __restrict__ lex_e,
    const int* __restrict__ seq_len, const int* __restrict__ lex_num,
    const float* __restrict__ Wq, const float* __restrict__ bq,
    const float* __restrict__ Wr, const float* __restrict__ br,
    const float* __restrict__ u_bias, const float* __restrict__ v_bias,
    const float* __restrict__ ln1_g, const float* __restrict__ ln1_b,
    const float* __restrict__ ln2_g, const float* __restrict__ ln2_b,
    const float* __restrict__ W1, const float* __restrict__ b1,
    const float* __restrict__ W2, const float* __restrict__ b2,
    const float* __restrict__ PEW, const float* __restrict__ kbuf, const float* __restrict__ vbuf,
    float* __restrict__ out) {

    __shared__ __align__(16) float s_x[H_], s_qu[H_], s_qv[H_];
    __shared__ __align__(16) float s_wvec[NH_][H_];
    __shared__ float s_bterm[NH_];
    __shared__ __align__(16) float s_sc[NH_][W_];
    __shared__ float s_red[H_];
    __shared__ __align__(16) float s_hid[FF_];
    __shared__ float s_tmp[256];
    __shared__ int s_ls[W_], s_le[W_];

    int blk = blockIdx.x;
    int b = blk / C_, c = blk % C_;
    int t = threadIdx.x;
    int lane = t & 63, wid = t >> 6;
    int l15 = lane & 15, quad = lane >> 4;

    if (t < H_) s_x[t] = chars[(b * C_ + c) * H_ + t];
    for (int w = t; w < W_; w += 256) {
        s_ls[w] = lex_s[b * W_ + w];
        s_le[w] = lex_e[b * W_ + w];
    }
    int ps = pos_s[b * C_ + c];
    int pev = pos_e[b * C_ + c];
    int cvalid = (c < seq_len[b]);
    int wnum = lex_num[b];
    __syncthreads();

    for (int li = 0; li < L_; ++li) {
        // ---- q projection: all 256 threads, K split in halves
        {
            int half = t >> 7, h = t & 127;
            const float* WqL = Wq + li * H_ * H_;
            const float4* x4 = (const float4*)s_x;
            float4 a4 = {0,0,0,0};
            for (int g = half * 16; g < half * 16 + 16; ++g) {
                float4 x = x4[g];
                int j0 = 4 * g;
                a4.x += x.x * WqL[(j0 + 0) * H_ + h];
                a4.y += x.y * WqL[(j0 + 1) * H_ + h];
                a4.z += x.z * WqL[(j0 + 2) * H_ + h];
                a4.w += x.w * WqL[(j0 + 3) * H_ + h];
            }
            s_tmp[t] = (a4.x + a4.y) + (a4.z + a4.w);
        }
        __syncthreads();
        if (t < H_) {
            float acc = s_tmp[t] + s_tmp[t + 128] + bq[li * H_ + t];
            s_qu[t] = acc + u_bias[li * H_ + t];
            s_qv[t] = acc + v_bias[li * H_ + t];
        }
        __syncthreads();

        // ---- wvec[n][h] = sum_p Wr[h][n*16+p]*qv[n*16+p];  bterm[n] = br[n*16..]·qv
        if (t < H_) {
            const float* WrRow = Wr + li * H_ * H_ + t * H_;
            for (int n = 0; n < NH_; ++n) {
                const float4* wr4 = (const float4*)(WrRow + n * PH_);
                const float4* qv4 = (const float4*)(s_qv + n * PH_);
                float4 a4 = {0,0,0,0};
                #pragma unroll
                for (int i = 0; i < 4; ++i) {
                    float4 wv_ = wr4[i], qv_ = qv4[i];
                    a4.x += wv_.x * qv_.x; a4.y += wv_.y * qv_.y;
                    a4.z += wv_.z * qv_.z; a4.w += wv_.w * qv_.w;
                }
                s_wvec[n][t] = (a4.x + a4.y) + (a4.z + a4.w);
            }
        } else if (t < H_ + NH_) {
            int n = t - H_;
            const float4* br4 = (const float4*)(br + li * H_ + n * PH_);
            const float4* qv4 = (const float4*)(s_qv + n * PH_);
            float4 a4 = {0,0,0,0};
            #pragma unroll
            for (int i = 0; i < 4; ++i) {
                float4 wv_ = br4[i], qv_ = qv4[i];
                a4.x += wv_.x * qv_.x; a4.y += wv_.y * qv_.y;
                a4.z += wv_.z * qv_.z; a4.w += wv_.w * qv_.w;
            }
            s_bterm[n] = (a4.x + a4.y) + (a4.z + a4.w);
        }
        __syncthreads();

        // ---- B fragments (wvec in bf16, MFMA B-layout), registers, reused all tiles
        bf16x8 Bfrag[4];
        {
            #pragma unroll
            for (int s = 0; s < 4; ++s) {
                bf16x8 f;
                int k0 = s * 32 + quad * 8;
                #pragma unroll
                for (int j = 0; j < 8; ++j)
                    f[j] = (l15 < NH_) ? (__bf16)s_wvec[l15][k0 + j] : (__bf16)(0.f);
                Bfrag[s] = f;
            }
        }

        // ---- B_D via MFMA: D[w,n] = sum_h relu(PEW gathers)[w,h] * wvec[n][h]
        // A-frag: m(w)=lane&15, k(h)=quad*8+j (+32*step); rel built in registers.
        for (int tile = wid; tile < (W_ + 15) / 16; tile += 4) {
            int w0 = tile * 16;
            int w = w0 + l15; if (w > W_ - 1) w = W_ - 1;
            int ls = s_ls[w], le = s_le[w];
            int i0 = min(max(ps - ls + MAXLEN_, 0), PEN_ - 1);
            int i1 = min(max(ps - le + MAXLEN_, 0), PEN_ - 1);
            int i2 = min(max(pev - ls + MAXLEN_, 0), PEN_ - 1);
            int i3 = min(max(pev - le + MAXLEN_, 0), PEN_ - 1);
            const float* r0 = PEW + (size_t)(0 * PEN_ + i0) * H_;
            const float* r1 = PEW + (size_t)(1 * PEN_ + i1) * H_;
            const float* r2 = PEW + (size_t)(2 * PEN_ + i2) * H_;
            const float* r3 = PEW + (size_t)(3 * PEN_ + i3) * H_;
            f32x4v acc = {0.f, 0.f, 0.f, 0.f};
            #pragma unroll
            for (int s = 0; s < 4; ++s) {
                int h0 = s * 32 + quad * 8;
                float4 a0 = *(const float4*)(r0 + h0), a1 = *(const float4*)(r0 + h0 + 4);
                float4 b0 = *(const float4*)(r1 + h0), b1_ = *(const float4*)(r1 + h0 + 4);
                float4 c0 = *(const float4*)(r2 + h0), c1 = *(const float4*)(r2 + h0 + 4);
                float4 d0 = *(const float4*)(r3 + h0), d1 = *(const float4*)(r3 + h0 + 4);
                bf16x8 A;
                A[0] = (__bf16)fmaxf(a0.x + b0.x + c0.x + d0.x, 0.f);
                A[1] = (__bf16)fmaxf(a0.y + b0.y + c0.y + d0.y, 0.f);
                A[2] = (__bf16)fmaxf(a0.z + b0.z + c0.z + d0.z, 0.f);
                A[3] = (__bf16)fmaxf(a0.w + b0.w + c0.w + d0.w, 0.f);
                A[4] = (__bf16)fmaxf(a1.x + b1_.x + c1.x + d1.x, 0.f);
                A[5] = (__bf16)fmaxf(a1.y + b1_.y + c1.y + d1.y, 0.f);
                A[6] = (__bf16)fmaxf(a1.z + b1_.z + c1.z + d1.z, 0.f);
                A[7] = (__bf16)fmaxf(a1.w + b1_.w + c1.w + d1.w, 0.f);
                acc = __builtin_amdgcn_mfma_f32_16x16x32_bf16(A, Bfrag[s], acc, 0, 0, 0);
            }
            // D: col(n)=lane&15, row(w-local)=quad*4+reg
            if (l15 < NH_) {
                #pragma unroll
                for (int r = 0; r < 4; ++r) {
                    int wr = w0 + quad * 4 + r;
                    if (wr < W_) s_sc[l15][wr] = acc[r];
                }
            }
        }
        __syncthreads();

        // ---- A_C + bterm: item i -> n = i&7, w = i>>3; k from global (L2)
        const float* kL = kbuf + (size_t)(li * B_ + b) * W_ * H_;
        for (int i = t; i < NH_ * W_; i += 256) {
            int n = i & 7, w = i >> 3;
            const float4* qu4 = (const float4*)(s_qu + n * PH_);
            const float4* kr4 = (const float4*)(kL + (size_t)w * H_ + n * PH_);
            float4 a4 = {0,0,0,0};
            #pragma unroll
            for (int j = 0; j < 4; ++j) {
                float4 q = qu4[j], k = kr4[j];
                a4.x += q.x * k.x; a4.y += q.y * k.y;
                a4.z += q.z * k.z; a4.w += q.w * k.w;
            }
            s_sc[n][w] += (a4.x + a4.y) + (a4.z + a4.w) + s_bterm[n];
        }
        __syncthreads();

        // ---- softmax per head (masked), att stored back into s_sc
        {
            int n = t >> 5, ln_ = t & 31;
            if (cvalid) {
                float m = -INFINITY;
                for (int w = ln_; w < wnum; w += 32) m = fmaxf(m, s_sc[n][w]);
                #pragma unroll
                for (int off = 16; off > 0; off >>= 1) m = fmaxf(m, __shfl_xor(m, off, 32));
                float sum = 0.f;
                for (int w = ln_; w < wnum; w += 32) sum += expf(s_sc[n][w] - m);
                #pragma unroll
                for (int off = 16; off > 0; off >>= 1) sum += __shfl_xor(sum, off, 32);
                float inv = 1.f / sum;
                for (int w = ln_; w < W_; w += 32)
                    s_sc[n][w] = (w < wnum) ? expf(s_sc[n][w] - m) * inv : 0.f;
            } else {
                for (int w = ln_; w < W_; w += 32) s_sc[n][w] = 0.f;
            }
        }
        __syncthreads();

        // ---- ctx = att @ v; halves split W; float4 att
        const float* vL = vbuf + (size_t)(li * B_ + b) * W_ * H_;
        {
            int h = t & 127, n = h >> 4;
            int half = t >> 7;
            int g0 = half ? 38 : 0, g1 = half ? 75 : 38;
            const float4* att4 = (const float4*)(s_sc[n]);
            float4 a4 = {0,0,0,0};
            for (int g = g0; g < g1; ++g) {
                float4 a = att4[g];
                int w = 4 * g;
                a4.x += a.x * vL[(size_t)(w + 0) * H_ + h];
                a4.y += a.y * vL[(size_t)(w + 1) * H_ + h];
                a4.z += a.z * vL[(size_t)(w + 2) * H_ + h];
                a4.w += a.w * vL[(size_t)(w + 3) * H_ + h];
            }
            s_tmp[t] = (a4.x + a4.y) + (a4.z + a4.w);
        }
        __syncthreads();

        // ---- LN1(ctx + x)
        float xln = 0.f;
        if (t < H_) xln = s_tmp[t] + s_tmp[t + 128] + s_x[t];
        float sum1 = block_sum_128(t, xln, s_red);
        float mean1 = sum1 * (1.f / 128.f);
        float d1 = xln - mean1;
        float vs1 = block_sum_128(t, (t < H_) ? d1 * d1 : 0.f, s_red);
        float rstd1 = rsqrtf(vs1 * (1.f / 128.f) + 1e-5f);
        if (t < H_)
            s_x[t] = d1 * rstd1 * ln1_g[li * H_ + t] + ln1_b[li * H_ + t];
        __syncthreads();

        // ---- FF hidden: thread t -> units (2t, 2t+1); float2 weight loads
        {
            const float* W1L = W1 + li * H_ * FF_;
            int u0 = t * 2;
            const float4* x4 = (const float4*)s_x;
            float4 a04 = {0,0,0,0}, a14 = {0,0,0,0};
            for (int g = 0; g < 32; ++g) {
                float4 x = x4[g];
                int j0 = 4 * g;
                float2 w0_ = *(const float2*)(W1L + (j0 + 0) * FF_ + u0);
                float2 w1_ = *(const float2*)(W1L + (j0 + 1) * FF_ + u0);
                float2 w2_ = *(const float2*)(W1L + (j0 + 2) * FF_ + u0);
                float2 w3_ = *(const float2*)(W1L + (j0 + 3) * FF_ + u0);
                a04.x += x.x * w0_.x; a14.x += x.x * w0_.y;
                a04.y += x.y * w1_.x; a14.y += x.y * w1_.y;
                a04.z += x.z * w2_.x; a14.z += x.z * w2_.y;
                a04.w += x.w * w3_.x; a14.w += x.w * w3_.y;
            }
            float a0 = (a04.x + a04.y) + (a04.z + a04.w) + b1[li * FF_ + u0];
            float a1 = (a14.x + a14.y) + (a14.z + a14.w) + b1[li * FF_ + u0 + 1];
            s_hid[u0] = fmaxf(a0, 0.f);
            s_hid[u0 + 1] = fmaxf(a1, 0.f);
        }
        __syncthreads();

        // ---- FF out: all 256 threads, K=512 split in halves
        {
            int half = t >> 7, h = t & 127;
            const float* W2L = W2 + li * FF_ * H_;
            const float4* h4 = (const float4*)s_hid;
            float4 a4 = {0,0,0,0};
            for (int g = half * 64; g < half * 64 + 64; ++g) {
                float4 hh = h4[g];
                int u = 4 * g;
                a4.x += hh.x * W2L[(u + 0) * H_ + h];
                a4.y += hh.y * W2L[(u + 1) * H_ + h];
                a4.z += hh.z * W2L[(u + 2) * H_ + h];
                a4.w += hh.w * W2L[(u + 3) * H_ + h];
            }
            s_tmp[t] = (a4.x + a4.y) + (a4.z + a4.w);
        }
        __syncthreads();
        float x2 = 0.f;
        if (t < H_) x2 = s_tmp[t] + s_tmp[t + 128] + b2[li * H_ + t] + s_x[t];
        float sum2 = block_sum_128(t, x2, s_red);
        float mean2 = sum2 * (1.f / 128.f);
        float d2 = x2 - mean2;
        float vs2 = block_sum_128(t, (t < H_) ? d2 * d2 : 0.f, s_red);
        float rstd2 = rsqrtf(vs2 * (1.f / 128.f) + 1e-5f);
        if (t < H_)
            s_x[t] = d2 * rstd2 * ln2_g[li * H_ + t] + ln2_b[li * H_ + t];
        __syncthreads();
    }

    if (t < H_) out[(b * C_ + c) * H_ + t] = s_x[t];
}

extern "C" void kernel_launch(void* const* d_in, const int* in_sizes, int n_in,
                              void* d_out, int out_size, void* d_ws, size_t ws_size,
                              hipStream_t stream) {
    const float* chars  = (const float*)d_in[0];
    const float* words  = (const float*)d_in[1];
    const int* pos_s   = (const int*)d_in[2];
    const int* pos_e   = (const int*)d_in[3];
    const int* lex_s   = (const int*)d_in[4];
    const int* lex_e   = (const int*)d_in[5];
    const int* seq_len = (const int*)d_in[6];
    const int* lex_num = (const int*)d_in[7];
    const float* Wf  = (const float*)d_in[8];
    const float* bfv = (const float*)d_in[9];
    const float* Wq  = (const float*)d_in[10];
    const float* bq  = (const float*)d_in[11];
    const float* Wk  = (const float*)d_in[12];
    const float* bk  = (const float*)d_in[13];
    const float* Wv  = (const float*)d_in[14];
    const float* bv  = (const float*)d_in[15];
    const float* Wr  = (const float*)d_in[16];
    const float* br  = (const float*)d_in[17];
    const float* u_bias = (const float*)d_in[18];
    const float* v_bias = (const float*)d_in[19];
    const float* ln1_g  = (const float*)d_in[20];
    const float* ln1_b  = (const float*)d_in[21];
    const float* ln2_g  = (const float*)d_in[22];
    const float* ln2_b  = (const float*)d_in[23];
    const float* W1  = (const float*)d_in[24];
    const float* b1  = (const float*)d_in[25];
    const float* W2  = (const float*)d_in[26];
    const float* b2  = (const float*)d_in[27];

    float* PEW  = (float*)d_ws;                    // 4*512*128 = 262144 floats
    float* kbuf = PEW + 4 * PEN_ * H_;             // 307200
    float* vbuf = kbuf + L_ * B_ * W_ * H_;        // 307200

    prep_kernel<<<dim3(PEN_ + L_ * B_ * W_), dim3(128), 0, stream>>>(
        Wf, bfv, words, Wk, bk, Wv, bv, PEW, kbuf, vbuf);

    mega_kernel<<<dim3(B_ * C_), dim3(256), 0, stream>>>(
        chars, pos_s, pos_e, lex_s, lex_e, seq_len, lex_num,
        Wq, bq, Wr, br, u_bias, v_bias,
        ln1_g, ln1_b, ln2_g, ln2_b, W1, b1, W2, b2,
        PEW, kbuf, vbuf, (float*)d_out);
}